// Round 1
// baseline (1070.818 us; speedup 1.0000x reference)
//
#include <hip/hip_runtime.h>
#include <math.h>

#define B_SZ 4096
#define N_SZ 200
#define K_SZ 64
#define H1 80
#define H2 40
#define NEG_V (-4294967295.0f)

// ---------------- Phase 1: qW[b][h] = b1[h] + sum_i q[b][i]*(W1[i][h]+W1[128+i][h])
__global__ __launch_bounds__(128) void qw_kernel(const float* __restrict__ query,
                                                 const float* __restrict__ W1,
                                                 const float* __restrict__ b1,
                                                 float* __restrict__ qW) {
    int b = blockIdx.x;
    int tid = threadIdx.x;
    __shared__ float sq[K_SZ];
    if (tid < K_SZ) sq[tid] = query[b * K_SZ + tid];
    __syncthreads();
    if (tid < H1) {
        float acc = b1[tid];
#pragma unroll 8
        for (int i = 0; i < K_SZ; ++i) {
            acc += sq[i] * (W1[i * H1 + tid] + W1[(128 + i) * H1 + tid]);
        }
        qW[b * H1 + tid] = acc;
    }
}

// ---------------- Phase 2: per-(b,n) score via 2-layer PReLU MLP
// h1 = prelu(qW[b] + k@W1k + (q*k)@W1p), W1k = W1[64:128]-W1[128:192], W1p = W1[192:256]
__global__ __launch_bounds__(256) void score_kernel(
    const float* __restrict__ query, const float* __restrict__ key,
    const int* __restrict__ mask,
    const float* __restrict__ W1, const float* __restrict__ a1,
    const float* __restrict__ W2, const float* __restrict__ b2,
    const float* __restrict__ a2,
    const float* __restrict__ Wo, const float* __restrict__ bo,
    const float* __restrict__ qW, float* __restrict__ scores) {
    __shared__ float sW1k[K_SZ * H1];   // [i][h]
    __shared__ float sW1p[K_SZ * H1];   // [i][h]
    __shared__ float sW2[H1 * H2];      // [j][m]
    __shared__ float sWo[H2];
    __shared__ float sb2[H2];
    __shared__ float sa2[H2];
    __shared__ float sa1[H1];
    __shared__ float sq[3 * K_SZ];      // up to 3 distinct b rows per block
    __shared__ float sqW[3 * H1];
    __shared__ float skc[16 * 256];     // k chunk [il][thread]

    const int tid = threadIdx.x;
    const int p0 = blockIdx.x * 256;
    const int p  = p0 + tid;            // pair index, always < B*N (grid exact)
    const int b  = p / N_SZ;
    const int bfirst = p0 / N_SZ;
    const int lb = b - bfirst;          // 0..2

    // ---- stage weights / params
    for (int idx = tid; idx < K_SZ * H1; idx += 256) {
        sW1k[idx] = W1[64 * H1 + idx] - W1[128 * H1 + idx];
        sW1p[idx] = W1[192 * H1 + idx];
    }
    for (int idx = tid; idx < H1 * H2; idx += 256) sW2[idx] = W2[idx];
    if (tid < H2) { sWo[tid] = Wo[tid]; sb2[tid] = b2[tid]; sa2[tid] = a2[tid]; }
    if (tid < H1) sa1[tid] = a1[tid];
    for (int idx = tid; idx < 3 * K_SZ; idx += 256) {
        int bb = bfirst + idx / K_SZ;
        sq[idx] = (bb < B_SZ) ? query[bb * K_SZ + (idx & 63)] : 0.0f;
    }
    for (int idx = tid; idx < 3 * H1; idx += 256) {
        int bb = bfirst + idx / H1;
        sqW[idx] = (bb < B_SZ) ? qW[bb * H1 + idx % H1] : 0.0f;
    }
    __syncthreads();

    // ---- init accumulator from per-b part
    float acc1[H1];
#pragma unroll
    for (int h = 0; h < H1; ++h) acc1[h] = sqW[lb * H1 + h];

    // ---- layer 1 over i-chunks of 16
    for (int c = 0; c < K_SZ; c += 16) {
        __syncthreads();  // protect previous chunk
        // stage skc[il][trow] = key[(p0+trow)*64 + c+il], float4 global loads
#pragma unroll
        for (int r = 0; r < 4; ++r) {
            int idx = r * 256 + tid;        // 0..1023
            int trow = idx >> 2;            // 0..255
            int il4 = (idx & 3) * 4;        // 0,4,8,12
            float4 v = *reinterpret_cast<const float4*>(
                &key[(size_t)(p0 + trow) * K_SZ + c + il4]);
            skc[(il4 + 0) * 256 + trow] = v.x;
            skc[(il4 + 1) * 256 + trow] = v.y;
            skc[(il4 + 2) * 256 + trow] = v.z;
            skc[(il4 + 3) * 256 + trow] = v.w;
        }
        __syncthreads();
#pragma unroll 2
        for (int il = 0; il < 16; ++il) {
            float kk = skc[il * 256 + tid];
            float qq = sq[lb * K_SZ + c + il];
            float pp = qq * kk;
#pragma unroll
            for (int h4 = 0; h4 < H1; h4 += 4) {
                float4 wk = *reinterpret_cast<const float4*>(&sW1k[(c + il) * H1 + h4]);
                float4 wp = *reinterpret_cast<const float4*>(&sW1p[(c + il) * H1 + h4]);
                acc1[h4 + 0] += kk * wk.x + pp * wp.x;
                acc1[h4 + 1] += kk * wk.y + pp * wp.y;
                acc1[h4 + 2] += kk * wk.z + pp * wp.z;
                acc1[h4 + 3] += kk * wk.w + pp * wp.w;
            }
        }
    }

    // ---- layer 2 (fully unrolled: all register indices static)
    float acc2[H2];
#pragma unroll
    for (int m = 0; m < H2; ++m) acc2[m] = sb2[m];
#pragma unroll
    for (int j = 0; j < H1; ++j) {
        float h = acc1[j];
        float hv = (h > 0.0f) ? h : sa1[j] * h;
#pragma unroll
        for (int m4 = 0; m4 < H2; m4 += 4) {
            float4 w = *reinterpret_cast<const float4*>(&sW2[j * H2 + m4]);
            acc2[m4 + 0] += hv * w.x;
            acc2[m4 + 1] += hv * w.y;
            acc2[m4 + 2] += hv * w.z;
            acc2[m4 + 3] += hv * w.w;
        }
    }

    // ---- output layer + mask
    float sc = bo[0];
#pragma unroll
    for (int m = 0; m < H2; ++m) {
        float h = acc2[m];
        float hv = (h > 0.0f) ? h : sa2[m] * h;
        sc += hv * sWo[m];
    }
    int mv = mask[p];
    scores[p] = (mv == 0) ? NEG_V : sc;
}

// ---------------- Phase 3: softmax over N + weighted value sum
__global__ __launch_bounds__(256) void softmax_out_kernel(
    const float* __restrict__ scores, const float* __restrict__ value,
    float* __restrict__ out) {
    int b = blockIdx.x;
    int tid = threadIdx.x;
    __shared__ float sprob[256];
    __shared__ float sred[8];
    __shared__ float spart[4 * K_SZ];

    float s = (tid < N_SZ) ? scores[b * N_SZ + tid] : -INFINITY;
    float m = s;
#pragma unroll
    for (int off = 32; off >= 1; off >>= 1) m = fmaxf(m, __shfl_xor(m, off));
    if ((tid & 63) == 0) sred[tid >> 6] = m;
    __syncthreads();
    m = fmaxf(fmaxf(sred[0], sred[1]), fmaxf(sred[2], sred[3]));

    float e = (tid < N_SZ) ? expf(s - m) : 0.0f;
    sprob[tid] = e;
    float t = e;
#pragma unroll
    for (int off = 32; off >= 1; off >>= 1) t += __shfl_xor(t, off);
    if ((tid & 63) == 0) sred[4 + (tid >> 6)] = t;
    __syncthreads();
    float inv = 1.0f / (sred[4] + sred[5] + sred[6] + sred[7]);

    // weighted sum: wave w covers n = [50w, 50w+50), lane = k index
    int w = tid >> 6;
    int l = tid & 63;
    float acc0 = 0.0f, acc1v = 0.0f;
#pragma unroll 5
    for (int jj = 0; jj < 50; jj += 2) {
        int n = w * 50 + jj;
        acc0  += sprob[n]     * value[((size_t)b * N_SZ + n)     * K_SZ + l];
        acc1v += sprob[n + 1] * value[((size_t)b * N_SZ + n + 1) * K_SZ + l];
    }
    spart[w * K_SZ + l] = acc0 + acc1v;
    __syncthreads();
    if (tid < K_SZ) {
        out[b * K_SZ + tid] =
            (spart[tid] + spart[64 + tid] + spart[128 + tid] + spart[192 + tid]) * inv;
    }
}

extern "C" void kernel_launch(void* const* d_in, const int* in_sizes, int n_in,
                              void* d_out, int out_size, void* d_ws, size_t ws_size,
                              hipStream_t stream) {
    const float* query = (const float*)d_in[0];
    const float* key   = (const float*)d_in[1];
    const float* value = (const float*)d_in[2];
    const int*   mask  = (const int*)d_in[3];
    const float* W1    = (const float*)d_in[4];
    const float* b1    = (const float*)d_in[5];
    const float* a1    = (const float*)d_in[6];
    const float* W2    = (const float*)d_in[7];
    const float* b2    = (const float*)d_in[8];
    const float* a2    = (const float*)d_in[9];
    const float* Wo    = (const float*)d_in[10];
    const float* bo    = (const float*)d_in[11];
    float* out = (float*)d_out;

    float* qW     = (float*)d_ws;                    // B*H1 floats
    float* scores = qW + (size_t)B_SZ * H1;          // B*N floats

    qw_kernel<<<B_SZ, 128, 0, stream>>>(query, W1, b1, qW);
    score_kernel<<<(B_SZ * N_SZ) / 256, 256, 0, stream>>>(
        query, key, mask, W1, a1, W2, b2, a2, Wo, bo, qW, scores);
    softmax_out_kernel<<<B_SZ, 256, 0, stream>>>(scores, value, out);
}